// Round 1
// baseline (268.923 us; speedup 1.0000x reference)
//
#include <hip/hip_runtime.h>
#include <math.h>

#define FL     8192
#define LOG2FL 13
#define BS     4096      // block step = FL/2
#define CD     16
#define BATCH  32
#define SEQ    262144
#define NB     64        // SEQ / BS

__device__ inline float2 cmul(float2 a, float2 b) {
    return make_float2(a.x * b.x - a.y * b.y, a.x * b.y + a.y * b.x);
}

// ---------------------------------------------------------------------------
// Kernel 1: H table per (batch, bin), stored in BIT-REVERSED bin order and
// pre-scaled by 1/FL (folds the ifft normalization).
// H[f] = sigmoid(c·Wf[f] + bf[f]) * exp(i*(c·Wp[f] + bp[f]))
// ---------------------------------------------------------------------------
__global__ void h_kernel(const float* __restrict__ c,
                         const float* __restrict__ Wf,
                         const float* __restrict__ bfv,
                         const float* __restrict__ Wp,
                         const float* __restrict__ bpv,
                         float2* __restrict__ H) {
    const int p = blockIdx.x * blockDim.x + threadIdx.x;   // LDS position 0..8191
    const int b = blockIdx.y;
    const int f = (int)(__brev((unsigned)p) >> (32 - LOG2FL)); // natural bin index

    float am = bfv[f];
    float ap = bpv[f];
#pragma unroll
    for (int i = 0; i < CD; ++i) {
        const float cv = c[b * CD + i];
        am += cv * Wf[f * CD + i];
        ap += cv * Wp[f * CD + i];
    }
    const float mag = 1.f / (1.f + __expf(-am));
    float sp, cp;
    sincosf(ap, &sp, &cp);
    const float s = mag * (1.f / (float)FL);
    H[(size_t)b * FL + p] = make_float2(s * cp, s * sp);
}

// ---------------------------------------------------------------------------
// Kernel 2: one workgroup per (block, batch).
// Load 4096 real samples (shifted by FL-1 zeros) -> fwd DIF radix-2 (13 stages,
// in-place, ends bit-reversed) -> pointwise * H (bit-rev order) -> inv DIT
// radix-2 (consumes bit-rev, natural output) -> atomic overlap-add.
// ---------------------------------------------------------------------------
__global__ __launch_bounds__(256) void fft_kernel(const float* __restrict__ x,
                                                  const float2* __restrict__ H,
                                                  float* __restrict__ out) {
    extern __shared__ float2 buf[];      // 8192 * 8 B = 64 KiB
    const int t   = threadIdx.x;
    const int blk = blockIdx.x;          // 0..NB-1
    const int b   = blockIdx.y;          // 0..BATCH-1
    const float* xb = x + (size_t)b * SEQ;

    // Load block: xp[blk*BS + k] = x[blk*BS + k - (FL-1)], zero-padded to FL.
#pragma unroll
    for (int r = 0; r < FL / 256; ++r) {
        const int k = t + 256 * r;
        float v = 0.f;
        if (k < BS) {
            const int u = blk * BS + k - (FL - 1);
            if (u >= 0) v = xb[u];
        }
        buf[k] = make_float2(v, 0.f);
    }

    // ---- forward DIF radix-2 ----
    for (int len = FL >> 1; len >= 1; len >>= 1) {
        __syncthreads();
#pragma unroll
        for (int r = 0; r < FL / 512; ++r) {
            const int bfly = t + 256 * r;
            const int j    = bfly & (len - 1);
            const int base = ((bfly - j) << 1) + j;
            const float2 a = buf[base];
            const float2 c2 = buf[base + len];
            const float2 s = make_float2(a.x + c2.x, a.y + c2.y);
            const float2 d = make_float2(a.x - c2.x, a.y - c2.y);
            const float ang = -3.14159265358979323846f * (float)j / (float)len;
            float sn, cs;
            __sincosf(ang, &sn, &cs);
            buf[base]       = s;
            buf[base + len] = make_float2(d.x * cs - d.y * sn, d.x * sn + d.y * cs);
        }
    }

    __syncthreads();
    // ---- pointwise multiply by H (both in bit-reversed order) ----
    const float2* Hb = H + (size_t)b * FL;
#pragma unroll
    for (int r = 0; r < FL / 256; ++r) {
        const int p = t + 256 * r;
        buf[p] = cmul(buf[p], Hb[p]);
    }

    // ---- inverse DIT radix-2 ----
    for (int len = 1; len <= (FL >> 1); len <<= 1) {
        __syncthreads();
#pragma unroll
        for (int r = 0; r < FL / 512; ++r) {
            const int bfly = t + 256 * r;
            const int j    = bfly & (len - 1);
            const int base = ((bfly - j) << 1) + j;
            const float2 a  = buf[base];
            const float2 c2 = buf[base + len];
            const float ang = 3.14159265358979323846f * (float)j / (float)len;
            float sn, cs;
            __sincosf(ang, &sn, &cs);
            const float2 bw = make_float2(c2.x * cs - c2.y * sn, c2.x * sn + c2.y * cs);
            buf[base]       = make_float2(a.x + bw.x, a.y + bw.y);
            buf[base + len] = make_float2(a.x - bw.x, a.y - bw.y);
        }
    }

    __syncthreads();
    // ---- overlap-add (each output element receives exactly 2 adds) ----
    float* outb = out + (size_t)b * SEQ;
#pragma unroll
    for (int r = 0; r < FL / 256; ++r) {
        const int p   = t + 256 * r;
        const int pos = blk * BS + p;
        if (pos < SEQ) atomicAdd(&outb[pos], buf[p].x);
    }
}

// ---------------------------------------------------------------------------
extern "C" void kernel_launch(void* const* d_in, const int* in_sizes, int n_in,
                              void* d_out, int out_size, void* d_ws, size_t ws_size,
                              hipStream_t stream) {
    const float* x   = (const float*)d_in[0];   // (B, S, 1)
    const float* c   = (const float*)d_in[1];   // (B, 1, 16)
    const float* Wf  = (const float*)d_in[2];   // (8192, 16)
    const float* bfv = (const float*)d_in[3];   // (8192,)
    const float* Wp  = (const float*)d_in[4];   // (8192, 16)
    const float* bpv = (const float*)d_in[5];   // (8192,)

    float*  out = (float*)d_out;
    float2* H   = (float2*)d_ws;                // BATCH * FL * 8 B = 2 MiB

    // zero the output (overlap-add accumulates into it)
    hipMemsetAsync(d_out, 0, (size_t)out_size * sizeof(float), stream);

    dim3 hgrid(FL / 256, BATCH);
    h_kernel<<<hgrid, 256, 0, stream>>>(c, Wf, bfv, Wp, bpv, H);

    dim3 fgrid(NB, BATCH);
    fft_kernel<<<fgrid, 256, FL * sizeof(float2), stream>>>(x, H, out);
}

// Round 4
// 170.633 us; speedup vs baseline: 1.5760x; 1.5760x over previous
//
#include <hip/hip_runtime.h>
#include <math.h>

#define FL     8192
#define BS     4096      // block step = FL/2
#define CD     16
#define BATCH  32
#define SEQ    262144
#define NPAIR  32        // 64 blocks -> 32 pairs
#define TWN    6144      // max twiddle exponent 3*2047

// LDS bank-pair swizzle (float2 = 8B = 2 banks; bank-pair index = i & 15)
__device__ __forceinline__ int SW(int i){ return i ^ ((i >> 4) & 15); }

__device__ __forceinline__ float2 cadd(float2 a, float2 b){ return make_float2(a.x+b.x, a.y+b.y); }
__device__ __forceinline__ float2 csub(float2 a, float2 b){ return make_float2(a.x-b.x, a.y-b.y); }
__device__ __forceinline__ float2 cmul(float2 a, float2 b){ return make_float2(a.x*b.x - a.y*b.y, a.x*b.y + a.y*b.x); }
// a * conj(b)
__device__ __forceinline__ float2 cmulc(float2 a, float2 b){ return make_float2(a.x*b.x + a.y*b.y, a.y*b.x - a.x*b.y); }

// Which natural bin f is stored at LDS position p after the DIF chain
// (radix-4 stages len=2048,512,128,32,8,2 then radix-2 len=1):
// f = q1 | q2<<2 | q3<<4 | q4<<6 | q5<<8 | q6<<10 | b<<12, digits from p top-down.
__device__ __forceinline__ int bin_of_pos(int p){
    return ((p>>11)&3) | (((p>>9)&3)<<2) | (((p>>7)&3)<<4) | (((p>>5)&3)<<6)
         | (((p>>3)&3)<<8) | (((p>>1)&3)<<10) | ((p&1)<<12);
}

// ---------------------------------------------------------------------------
// Master twiddle table: T[k] = e^{-2*pi*i*k/FL}, k in [0, TWN)
// ---------------------------------------------------------------------------
__global__ void tw_kernel(float2* __restrict__ T){
    int k = blockIdx.x*256 + threadIdx.x;
    if (k < TWN){
        double a = -2.0 * M_PI * (double)k / (double)FL;
        T[k] = make_float2((float)cos(a), (float)sin(a));
    }
}

// ---------------------------------------------------------------------------
// Heff per (batch, position): Heff[f] = (H[f] + conj(H[(N-f)%N]))/2 * (1/N),
// stored at the digit-reversed position p (and pre-scaled by 1/N).
// Conj-symmetric filter => real operator => two real blocks per complex FFT.
// ---------------------------------------------------------------------------
__global__ void h_kernel(const float* __restrict__ c,  const float* __restrict__ Wf,
                         const float* __restrict__ bfv, const float* __restrict__ Wp,
                         const float* __restrict__ bpv, float2* __restrict__ H){
    const int p = blockIdx.x*256 + threadIdx.x;
    const int b = blockIdx.y;
    const int f = bin_of_pos(p);
    const int g = (FL - f) & (FL - 1);
    float amf = bfv[f], apf = bpv[f], amg = bfv[g], apg = bpv[g];
#pragma unroll
    for (int i=0;i<CD;++i){
        const float cv = c[b*CD + i];
        amf += cv * Wf[f*CD + i];
        apf += cv * Wp[f*CD + i];
        amg += cv * Wf[g*CD + i];
        apg += cv * Wp[g*CD + i];
    }
    const float magf = 1.f/(1.f+__expf(-amf));
    const float magg = 1.f/(1.f+__expf(-amg));
    float sf, cf2, sg, cg2;
    __sincosf(apf, &sf, &cf2);
    __sincosf(apg, &sg, &cg2);
    const float scale = 0.5f / (float)FL;
    H[(size_t)b*FL + p] = make_float2((magf*cf2 + magg*cg2)*scale,
                                      (magf*sf  - magg*sg )*scale);
}

// ---------------------------------------------------------------------------
// Radix-4 DIF forward stage (negative exponent), twiddle after DFT4.
// ---------------------------------------------------------------------------
template<int LEN, int LG>
__device__ __forceinline__ void r4_fwd(float2* buf, const float2* __restrict__ T, int t){
#pragma unroll
    for (int it=0; it<8; ++it){
        const int bfly = t + 256*it;
        const int j    = bfly & (LEN-1);
        const int base = ((bfly - j) << 2) + j;
        const int e1   = j << (11 - LG);
        const float2 a0 = buf[SW(base)];
        const float2 a1 = buf[SW(base+LEN)];
        const float2 a2 = buf[SW(base+2*LEN)];
        const float2 a3 = buf[SW(base+3*LEN)];
        const float2 w1 = T[e1], w2 = T[2*e1], w3 = T[3*e1];
        const float2 t0 = cadd(a0,a2), t1 = csub(a0,a2);
        const float2 t2 = cadd(a1,a3), t3 = csub(a1,a3);
        const float2 mi3 = make_float2( t3.y, -t3.x);   // -i*t3
        const float2 pi3 = make_float2(-t3.y,  t3.x);   // +i*t3
        buf[SW(base)]       = cadd(t0,t2);
        buf[SW(base+LEN)]   = cmul(cadd(t1,mi3), w1);
        buf[SW(base+2*LEN)] = cmul(csub(t0,t2), w2);
        buf[SW(base+3*LEN)] = cmul(cadd(t1,pi3), w3);
    }
}

// ---------------------------------------------------------------------------
// Radix-4 DIT inverse stage (positive exponent), conj-twiddle before IDFT4.
// ---------------------------------------------------------------------------
template<int LEN, int LG>
__device__ __forceinline__ void r4_inv(float2* buf, const float2* __restrict__ T, int t){
#pragma unroll
    for (int it=0; it<8; ++it){
        const int bfly = t + 256*it;
        const int j    = bfly & (LEN-1);
        const int base = ((bfly - j) << 2) + j;
        const int e1   = j << (11 - LG);
        float2 c0 = buf[SW(base)];
        float2 c1 = buf[SW(base+LEN)];
        float2 c2 = buf[SW(base+2*LEN)];
        float2 c3 = buf[SW(base+3*LEN)];
        const float2 w1 = T[e1], w2 = T[2*e1], w3 = T[3*e1];
        c1 = cmulc(c1, w1); c2 = cmulc(c2, w2); c3 = cmulc(c3, w3);
        const float2 u0 = cadd(c0,c2), u1 = csub(c0,c2);
        const float2 u2 = cadd(c1,c3), u3 = csub(c1,c3);
        const float2 piu = make_float2(-u3.y,  u3.x);   // +i*u3
        const float2 miu = make_float2( u3.y, -u3.x);   // -i*u3
        buf[SW(base)]       = cadd(u0,u2);
        buf[SW(base+LEN)]   = cadd(u1,piu);
        buf[SW(base+2*LEN)] = csub(u0,u2);
        buf[SW(base+3*LEN)] = cadd(u1,miu);
    }
}

// Radix-2 stage on adjacent pairs (len=1, twiddle-free; same fwd & inv).
__device__ __forceinline__ void r2_stage(float2* buf, int t){
#pragma unroll
    for (int it=0; it<16; ++it){
        const int base = 2*(t + 256*it);
        const float2 a = buf[SW(base)], b = buf[SW(base+1)];
        buf[SW(base)]   = cadd(a,b);
        buf[SW(base+1)] = csub(a,b);
    }
}

// ---------------------------------------------------------------------------
// One WG per (block-pair, batch): pack blocks (2pr, 2pr+1) as re+im,
// fwd FFT -> *Heff -> inv FFT -> overlap-add (Re -> block a, Im -> block b).
// ---------------------------------------------------------------------------
__global__ __launch_bounds__(256) void fft_kernel(const float*  __restrict__ x,
                                                  const float2* __restrict__ H,
                                                  const float2* __restrict__ T,
                                                  float* __restrict__ out){
    extern __shared__ float2 buf[];      // 8192 * 8B = 64 KiB
    const int t  = threadIdx.x;
    const int pr = blockIdx.x;           // pair index 0..31
    const int b  = blockIdx.y;
    const float* xb = x + (size_t)b*SEQ;
    const int s0 = 2*pr*BS - (FL-1);

#pragma unroll
    for (int r=0;r<FL/256;++r){
        const int k = t + 256*r;
        float va=0.f, vb=0.f;
        if (k < BS){
            const int ua = s0 + k, ub = ua + BS;
            if (ua >= 0) va = xb[ua];
            if (ub >= 0) vb = xb[ub];
        }
        buf[SW(k)] = make_float2(va,vb);
    }
    __syncthreads();

    r4_fwd<2048,11>(buf,T,t); __syncthreads();
    r4_fwd<512, 9>(buf,T,t);  __syncthreads();
    r4_fwd<128, 7>(buf,T,t);  __syncthreads();
    r4_fwd<32,  5>(buf,T,t);  __syncthreads();
    r4_fwd<8,   3>(buf,T,t);  __syncthreads();
    r4_fwd<2,   1>(buf,T,t);  __syncthreads();
    r2_stage(buf,t);          __syncthreads();

    const float2* Hb = H + (size_t)b*FL;
#pragma unroll
    for (int r=0;r<FL/256;++r){
        const int p = t + 256*r;
        buf[SW(p)] = cmul(buf[SW(p)], Hb[p]);
    }
    __syncthreads();

    r2_stage(buf,t);          __syncthreads();
    r4_inv<2,   1>(buf,T,t);  __syncthreads();
    r4_inv<8,   3>(buf,T,t);  __syncthreads();
    r4_inv<32,  5>(buf,T,t);  __syncthreads();
    r4_inv<128, 7>(buf,T,t);  __syncthreads();
    r4_inv<512, 9>(buf,T,t);  __syncthreads();
    r4_inv<2048,11>(buf,T,t); __syncthreads();

    // Overlap-add. Span layout (spans of BS outputs):
    //   span 2pr   (even): y_a[0:BS]            -> atomic (also hit by WG pr-1)
    //   span 2pr+1 (odd):  y_a[BS:FL]+y_b[0:BS] -> SOLE writer -> plain store
    //   span 2pr+2 (even): y_b[BS:FL]           -> atomic (also hit by WG pr+1)
    float* ob = out + (size_t)b*SEQ;
    const int pa = 2*pr*BS;
#pragma unroll
    for (int r=0;r<BS/256;++r){
        const int k = t + 256*r;
        const float2 wlo = buf[SW(k)];
        const float2 whi = buf[SW(k+BS)];
        atomicAdd(&ob[pa+k], wlo.x);
        ob[pa+BS+k] = whi.x + wlo.y;
        const int p3 = pa + 2*BS + k;
        if (p3 < SEQ) atomicAdd(&ob[p3], whi.y);
    }
}

// ---------------------------------------------------------------------------
extern "C" void kernel_launch(void* const* d_in, const int* in_sizes, int n_in,
                              void* d_out, int out_size, void* d_ws, size_t ws_size,
                              hipStream_t stream) {
    const float* x   = (const float*)d_in[0];
    const float* c   = (const float*)d_in[1];
    const float* Wf  = (const float*)d_in[2];
    const float* bfv = (const float*)d_in[3];
    const float* Wp  = (const float*)d_in[4];
    const float* bpv = (const float*)d_in[5];

    float*  out = (float*)d_out;
    float2* H   = (float2*)d_ws;                                  // 2 MiB
    float2* T   = (float2*)((char*)d_ws + (size_t)BATCH*FL*sizeof(float2));

    hipMemsetAsync(d_out, 0, (size_t)out_size*sizeof(float), stream);

    tw_kernel<<<(TWN+255)/256, 256, 0, stream>>>(T);
    h_kernel<<<dim3(FL/256, BATCH), 256, 0, stream>>>(c, Wf, bfv, Wp, bpv, H);
    fft_kernel<<<dim3(NPAIR, BATCH), 256, FL*sizeof(float2), stream>>>(x, H, T, out);
}

// Round 5
// 103.095 us; speedup vs baseline: 2.6085x; 1.6551x over previous
//
#include <hip/hip_runtime.h>
#include <math.h>

#define FL     8192
#define BS     4096      // block step = FL/2
#define CD     16
#define BATCH  32
#define SEQ    262144
#define NPAIR  32        // 64 blocks -> 32 pairs

// LDS bank-pair swizzle (float2 = 8B = 2 banks; bank-pair index = i & 15)
__device__ __forceinline__ int SW(int i){ return i ^ ((i >> 4) & 15); }

__device__ __forceinline__ float2 cadd(float2 a, float2 b){ return make_float2(a.x+b.x, a.y+b.y); }
__device__ __forceinline__ float2 csub(float2 a, float2 b){ return make_float2(a.x-b.x, a.y-b.y); }
__device__ __forceinline__ float2 cmul(float2 a, float2 b){ return make_float2(a.x*b.x - a.y*b.y, a.x*b.y + a.y*b.x); }
// a * (c + i s)
__device__ __forceinline__ float2 mri(float2 a, float c, float s){ return make_float2(a.x*c - a.y*s, a.x*s + a.y*c); }

// Digit-reversed bin stored at position p after DIF passes
// A(R16,s512), B(R16,s32), C(R2,s16), D(R16,s1):
// k = qA + 16*qB + 256*qC + 512*qD ; p = 512*qA + 32*qB + 16*qC + qD
__device__ __forceinline__ int bin_of_pos(int p){
    return ((p>>9)&15) | (((p>>5)&15)<<4) | (((p>>4)&1)<<8) | ((p&15)<<9);
}

// ---------------------------------------------------------------------------
// In-register 16-point DFT, natural order in/out, 4x4 Cooley-Tukey.
// INV: conjugate (inverse, unnormalized). HALF: inputs d[8..15] are zero.
// ---------------------------------------------------------------------------
template<bool INV, bool HALF>
__device__ __forceinline__ void dft16(float2* d){
    constexpr float sgn = INV ? 1.f : -1.f;          // e^{sgn*i*2pi*k/16}
    constexpr float C1 = 0.923879532511287f;          // cos(pi/8)
    constexpr float S1 = 0.382683432365090f;          // sin(pi/8)
    constexpr float R  = 0.707106781186548f;
    float2 u[16];
    // step 1: DFT-4 over a (inputs d[4a+b]) for each b
#pragma unroll
    for (int b=0;b<4;++b){
        const float2 a0=d[b], a1=d[4+b];
        if (HALF){
            const float2 ja1 = make_float2(-sgn*a1.y, sgn*a1.x);
            u[4*b+0]=cadd(a0,a1);
            u[4*b+1]=cadd(a0,ja1);
            u[4*b+2]=csub(a0,a1);
            u[4*b+3]=csub(a0,ja1);
        } else {
            const float2 a2=d[8+b], a3=d[12+b];
            const float2 s0=cadd(a0,a2), s1=csub(a0,a2);
            const float2 s2=cadd(a1,a3), s3=csub(a1,a3);
            const float2 js3 = make_float2(-sgn*s3.y, sgn*s3.x);
            u[4*b+0]=cadd(s0,s2);
            u[4*b+1]=cadd(s1,js3);
            u[4*b+2]=csub(s0,s2);
            u[4*b+3]=csub(s1,js3);
        }
    }
    // step 2: twiddle u[4b+c] *= e^{sgn*i*2pi*b*c/16}
    u[4+1] = mri(u[4+1],  C1, sgn*S1);
    u[4+2] = mri(u[4+2],  R,  sgn*R );
    u[4+3] = mri(u[4+3],  S1, sgn*C1);
    u[8+1] = mri(u[8+1],  R,  sgn*R );
    u[8+2] = mri(u[8+2],  0.f, sgn);
    u[8+3] = mri(u[8+3], -R,  sgn*R );
    u[12+1]= mri(u[12+1], S1, sgn*C1);
    u[12+2]= mri(u[12+2],-R,  sgn*R );
    u[12+3]= mri(u[12+3],-C1,-sgn*S1);
    // step 3: DFT-4 over b for each c -> X[c+4d2]
#pragma unroll
    for (int c=0;c<4;++c){
        const float2 a0=u[c], a1=u[4+c], a2=u[8+c], a3=u[12+c];
        const float2 s0=cadd(a0,a2), s1=csub(a0,a2);
        const float2 s2=cadd(a1,a3), s3=csub(a1,a3);
        const float2 js3 = make_float2(-sgn*s3.y, sgn*s3.x);
        d[c+0] =cadd(s0,s2);
        d[c+4] =cadd(s1,js3);
        d[c+8] =csub(s0,s2);
        d[c+12]=csub(s1,js3);
    }
}

// chained twiddle: d[q] *= w1^q, q=1..15
__device__ __forceinline__ void twiddle_chain(float2* d, float2 w1){
    float2 wq = w1;
    d[1] = cmul(d[1], wq);
#pragma unroll
    for (int q=2;q<16;++q){ wq = cmul(wq, w1); d[q] = cmul(d[q], wq); }
}

// ---------------------------------------------------------------------------
// Heff per (batch, position): Heff[f] = (H[f] + conj(H[(N-f)%N]))/2 / N,
// stored at digit-reversed position p.
// ---------------------------------------------------------------------------
__global__ void h_kernel(const float* __restrict__ c,  const float* __restrict__ Wf,
                         const float* __restrict__ bfv, const float* __restrict__ Wp,
                         const float* __restrict__ bpv, float2* __restrict__ H){
    const int p = blockIdx.x*256 + threadIdx.x;
    const int b = blockIdx.y;
    const int f = bin_of_pos(p);
    const int g = (FL - f) & (FL - 1);
    float amf = bfv[f], apf = bpv[f], amg = bfv[g], apg = bpv[g];
#pragma unroll
    for (int i=0;i<CD;++i){
        const float cv = c[b*CD + i];
        amf += cv * Wf[f*CD + i];
        apf += cv * Wp[f*CD + i];
        amg += cv * Wf[g*CD + i];
        apg += cv * Wp[g*CD + i];
    }
    const float magf = 1.f/(1.f+__expf(-amf));
    const float magg = 1.f/(1.f+__expf(-amg));
    float sf, cf2, sg, cg2;
    __sincosf(apf, &sf, &cf2);
    __sincosf(apg, &sg, &cg2);
    const float scale = 0.5f / (float)FL;
    H[(size_t)b*FL + p] = make_float2((magf*cf2 + magg*cg2)*scale,
                                      (magf*sf  - magg*sg )*scale);
}

// ---------------------------------------------------------------------------
// One WG (512 thr) per (block-pair, batch). Register-resident mixed-radix FFT:
// A: global->reg, DFT16(half), tw W_8192^{jq}, ->LDS   (stride 512)
// B: LDS DFT16 + tw W_512^{jq}                          (stride 32)
// C: radix-2 + tw W_32^j                                (stride 16)
// D: DFT16 x Heff x IDFT16 fused                        (stride 1)
// C',B': mirrors with conj twiddles
// A': LDS->reg, conj tw, IDFT16, overlap-add -> global
// ---------------------------------------------------------------------------
__global__ __launch_bounds__(512, 4) void fft_kernel(const float*  __restrict__ x,
                                                     const float2* __restrict__ H,
                                                     float* __restrict__ out){
    extern __shared__ float2 buf[];      // 8192 * 8B = 64 KiB
    const int t  = threadIdx.x;
    const int pr = blockIdx.x;
    const int b  = blockIdx.y;
    const float* xb = x + (size_t)b*SEQ;
    const int s0 = 2*pr*BS - (FL-1);
    const float TWO_PI = 6.28318530717958647692f;

    float2 d[16];

    // cos/sin(pi*k/16) tables for W_32^k (folded to literals under unroll)
    constexpr float CT[16] = { 1.f, 0.980785280403230f, 0.923879532511287f, 0.831469612302545f,
                               0.707106781186548f, 0.555570233019602f, 0.382683432365090f, 0.195090322016128f,
                               0.f,-0.195090322016128f,-0.382683432365090f,-0.555570233019602f,
                              -0.707106781186548f,-0.831469612302545f,-0.923879532511287f,-0.980785280403230f };
    constexpr float ST[16] = { 0.f, 0.195090322016128f, 0.382683432365090f, 0.555570233019602f,
                               0.707106781186548f, 0.831469612302545f, 0.923879532511287f, 0.980785280403230f,
                               1.f, 0.980785280403230f, 0.923879532511287f, 0.831469612302545f,
                               0.707106781186548f, 0.555570233019602f, 0.382683432365090f, 0.195090322016128f };

    // ---- Pass A: radix-16, stride 512 (input half-zero) ----
    {
        const int j = t;
#pragma unroll
        for (int m=0;m<8;++m){
            const int k  = j + 512*m;          // < 4096 always
            const int ua = s0 + k, ub = ua + BS;
            float va = (ua >= 0) ? xb[ua] : 0.f;
            float vb = (ub >= 0) ? xb[ub] : 0.f;
            d[m] = make_float2(va, vb);
        }
        dft16<false,true>(d);
        float snv, csv; __sincosf(-TWO_PI * (float)j / 8192.f, &snv, &csv);
        twiddle_chain(d, make_float2(csv, snv));
#pragma unroll
        for (int q=0;q<16;++q) buf[SW(j + 512*q)] = d[q];
    }
    __syncthreads();

    // ---- Pass B: radix-16, stride 32 ----
    {
        const int base = ((t>>5)<<9) + (t&31);
        const int j = t&31;
#pragma unroll
        for (int m=0;m<16;++m) d[m] = buf[SW(base + 32*m)];
        dft16<false,false>(d);
        float snv, csv; __sincosf(-TWO_PI * (float)j / 512.f, &snv, &csv);
        twiddle_chain(d, make_float2(csv, snv));
#pragma unroll
        for (int q=0;q<16;++q) buf[SW(base + 32*q)] = d[q];
    }
    __syncthreads();

    // ---- Pass C: radix-2, stride 16, tw W_32^j on odd output ----
    {
        const int r = t&1, base = 32*(t>>1) + 8*r;
#pragma unroll
        for (int jj=0;jj<8;++jj){
            const int i0 = base + jj;
            const float2 a = buf[SW(i0)], bb = buf[SW(i0+16)];
            const float ck = r ? CT[jj+8] : CT[jj];
            const float sk = r ? ST[jj+8] : ST[jj];
            buf[SW(i0)]    = cadd(a,bb);
            buf[SW(i0+16)] = mri(csub(a,bb), ck, -sk);
        }
    }
    __syncthreads();

    // ---- Pass D: DFT16 x Heff x IDFT16, contiguous 16-block ----
    {
        const int base = t<<4;
#pragma unroll
        for (int i=0;i<16;++i) d[i] = buf[SW(base+i)];
        dft16<false,false>(d);
        const float4* H4 = reinterpret_cast<const float4*>(H + (size_t)b*FL + base);
#pragma unroll
        for (int q=0;q<8;++q){
            const float4 hv = H4[q];
            d[2*q]   = cmul(d[2*q],   make_float2(hv.x, hv.y));
            d[2*q+1] = cmul(d[2*q+1], make_float2(hv.z, hv.w));
        }
        dft16<true,false>(d);
#pragma unroll
        for (int i=0;i<16;++i) buf[SW(base+i)] = d[i];
    }
    __syncthreads();

    // ---- Pass C': inverse radix-2, stride 16, conj tw before butterfly ----
    {
        const int r = t&1, base = 32*(t>>1) + 8*r;
#pragma unroll
        for (int jj=0;jj<8;++jj){
            const int i0 = base + jj;
            const float2 a = buf[SW(i0)], bb = buf[SW(i0+16)];
            const float ck = r ? CT[jj+8] : CT[jj];
            const float sk = r ? ST[jj+8] : ST[jj];
            const float2 tb = mri(bb, ck, sk);
            buf[SW(i0)]    = cadd(a,tb);
            buf[SW(i0+16)] = csub(a,tb);
        }
    }
    __syncthreads();

    // ---- Pass B': inverse radix-16, stride 32 ----
    {
        const int base = ((t>>5)<<9) + (t&31);
        const int j = t&31;
#pragma unroll
        for (int q=0;q<16;++q) d[q] = buf[SW(base + 32*q)];
        float snv, csv; __sincosf(TWO_PI * (float)j / 512.f, &snv, &csv);
        twiddle_chain(d, make_float2(csv, snv));
        dft16<true,false>(d);
#pragma unroll
        for (int m=0;m<16;++m) buf[SW(base + 32*m)] = d[m];
    }
    __syncthreads();

    // ---- Pass A': inverse radix-16, stride 512 + overlap-add to global ----
    {
        const int j = t;
#pragma unroll
        for (int q=0;q<16;++q) d[q] = buf[SW(j + 512*q)];
        float snv, csv; __sincosf(TWO_PI * (float)j / 8192.f, &snv, &csv);
        twiddle_chain(d, make_float2(csv, snv));
        dft16<true,false>(d);
        // d[m] = y[time j + 512*m]; Re -> block a, Im -> block b
        float* ob = out + (size_t)b*SEQ;
        const int pa = 2*pr*BS;
#pragma unroll
        for (int mm=0;mm<8;++mm){
            const int klo = j + 512*mm;
            atomicAdd(&ob[pa+klo], d[mm].x);                 // even span (2 writers)
            ob[pa+BS+klo] = d[mm+8].x + d[mm].y;             // odd span (sole writer)
            const int p3 = pa + 2*BS + klo;
            if (p3 < SEQ) atomicAdd(&ob[p3], d[mm+8].y);     // even span (2 writers)
        }
    }
}

// ---------------------------------------------------------------------------
extern "C" void kernel_launch(void* const* d_in, const int* in_sizes, int n_in,
                              void* d_out, int out_size, void* d_ws, size_t ws_size,
                              hipStream_t stream) {
    const float* x   = (const float*)d_in[0];
    const float* c   = (const float*)d_in[1];
    const float* Wf  = (const float*)d_in[2];
    const float* bfv = (const float*)d_in[3];
    const float* Wp  = (const float*)d_in[4];
    const float* bpv = (const float*)d_in[5];

    float*  out = (float*)d_out;
    float2* H   = (float2*)d_ws;                      // BATCH*FL*8B = 2 MiB

    hipMemsetAsync(d_out, 0, (size_t)out_size*sizeof(float), stream);
    h_kernel<<<dim3(FL/256, BATCH), 256, 0, stream>>>(c, Wf, bfv, Wp, bpv, H);
    fft_kernel<<<dim3(NPAIR, BATCH), 512, FL*sizeof(float2), stream>>>(x, H, out);
}